// Round 1
// baseline (272.690 us; speedup 1.0000x reference)
//
#include <hip/hip_runtime.h>
#include <stdint.h>

typedef unsigned long long u64;

#define THRESH_F 5e-5f
#define BB 128
#define HH 384
#define WW_ 384
#define WPR 6                       // u64 words per 384-pixel row
#define ROWS_TOTAL (BB*HH)          // 49152
#define WORDS_TOTAL (ROWS_TOTAL*WPR)// 294912
#define OH 378
#define OW 378
#define PIX (BB*HH*WW_)             // 18874368
#define COVN (49.0f/48.0f)

// ---------------- K1: binarize Y -> bitmask via wave ballot ----------------
__global__ void k_binarize(const float* __restrict__ Y, u64* __restrict__ bits) {
    int idx = blockIdx.x * 256 + threadIdx.x;         // grid exact: PIX/256
    float y = Y[idx];
    u64 bal = __ballot(y > THRESH_F);
    if ((threadIdx.x & 63) == 0) bits[idx >> 6] = bal;
}

// ---------------- K2: 3x3 erosion on bits (fused h+v), OOB treated as 1 ----
__device__ __forceinline__ u64 erode_h1(u64 a, u64 b, u64 c, int ww) {
    u64 l = (b << 1) | ((ww > 0) ? (a >> 63) : 1ull);
    u64 r = (b >> 1) | ((ww < WPR - 1) ? (c << 63) : (1ull << 63));
    return b & l & r;
}

__global__ void k_erode3(const u64* __restrict__ in, u64* __restrict__ out) {
    int w = blockIdx.x * 256 + threadIdx.x;           // grid exact: WORDS_TOTAL/256
    int row = w / WPR;
    int ww = w - row * WPR;
    int r = row % HH;
    u64 res = ~0ull;
    #pragma unroll
    for (int dr = -1; dr <= 1; ++dr) {
        int rr = r + dr;
        if (rr < 0 || rr >= HH) continue;             // OOB row = all ones (ignored by AND)
        const u64* rowp = in + (size_t)(row + dr) * WPR;
        u64 a = (ww > 0) ? rowp[ww - 1] : 0ull;
        u64 b = rowp[ww];
        u64 c = (ww < WPR - 1) ? rowp[ww + 1] : 0ull;
        res &= erode_h1(a, b, c, ww);
    }
    out[w] = res;
}

// ---------------- K3: horizontal dilate radius 15 (bitstream OR-doubling) --
__global__ void k_dilate_h15(const u64* __restrict__ in, u64* __restrict__ out) {
    int w = blockIdx.x * 256 + threadIdx.x;
    int row = w / WPR;
    int ww = w - row * WPR;
    const u64* rowp = in + (size_t)row * WPR;
    u64 a = (ww > 0) ? rowp[ww - 1] : 0ull;           // OOB = 0 for dilation
    u64 b = rowp[ww];
    u64 c = (ww < WPR - 1) ? rowp[ww + 1] : 0ull;
    __uint128_t X = (((__uint128_t)b) << 64) | a;     // left shifts 0..15
    X |= X << 1; X |= X << 2; X |= X << 4; X |= X << 8;
    __uint128_t Z = (((__uint128_t)c) << 64) | b;     // right shifts 0..15
    Z |= Z >> 1; Z |= Z >> 2; Z |= Z >> 4; Z |= Z >> 8;
    out[w] = (u64)(X >> 64) | (u64)Z;
}

// ---------------- K4: vertical dilate radius 15 ----------------------------
__global__ void k_dilate_v15(const u64* __restrict__ in, u64* __restrict__ out) {
    int w = blockIdx.x * 256 + threadIdx.x;
    int row = w / WPR;
    int ww = w - row * WPR;
    int r = row % HH;
    int base = row - r;
    int lo = r - 15; if (lo < 0) lo = 0;
    int hi = r + 15; if (hi > HH - 1) hi = HH - 1;
    u64 acc = 0ull;
    for (int rr = lo; rr <= hi; ++rr) acc |= in[(size_t)(base + rr) * WPR + ww];
    out[w] = acc;
}

// ---------------- K5: horizontal erode radius 14 (complement-dilate) -------
__global__ void k_erode_h14(const u64* __restrict__ in, u64* __restrict__ out) {
    int w = blockIdx.x * 256 + threadIdx.x;
    int row = w / WPR;
    int ww = w - row * WPR;
    const u64* rowp = in + (size_t)row * WPR;
    u64 a = (ww > 0) ? rowp[ww - 1] : ~0ull;          // OOB = 1 for erosion
    u64 b = rowp[ww];
    u64 c = (ww < WPR - 1) ? rowp[ww + 1] : ~0ull;
    u64 na = ~a, nb = ~b, nc = ~c;
    __uint128_t X = (((__uint128_t)nb) << 64) | na;   // shifts 0..14: 0..7 then |<<7
    X |= X << 1; X |= X << 2; X |= X << 4; X |= X << 7;
    __uint128_t Z = (((__uint128_t)nc) << 64) | nb;
    Z |= Z >> 1; Z |= Z >> 2; Z |= Z >> 4; Z |= Z >> 7;
    out[w] = ~((u64)(X >> 64) | (u64)Z);
}

// ---------------- K6: vertical erode radius 14 (final mask) ----------------
__global__ void k_erode_v14(const u64* __restrict__ in, u64* __restrict__ out) {
    int w = blockIdx.x * 256 + threadIdx.x;
    int row = w / WPR;
    int ww = w - row * WPR;
    int r = row % HH;
    int base = row - r;
    int lo = r - 14; if (lo < 0) lo = 0;
    int hi = r + 14; if (hi > HH - 1) hi = HH - 1;
    u64 acc = ~0ull;
    for (int rr = lo; rr <= hi; ++rr) acc &= in[(size_t)(base + rr) * WPR + ww];
    out[w] = acc;
}

// ---------------- K7: fused masked SSIM with vertical register slider ------
// grid (6, 3, 128), block 256: 64 columns x 4 chunk-slots per block.
// Each thread: one output column j, 32 output rows (chunk), ring buffer of
// horizontal 7-sums for 5 quantities, sliding vertical sum.
__global__ void __launch_bounds__(256) k_ssim(
    const float* __restrict__ Xg, const float* __restrict__ Yg,
    const float* __restrict__ drg, const u64* __restrict__ Mg,
    float* __restrict__ accum)
{
    const int tx = threadIdx.x & 63;
    const int cz = threadIdx.x >> 6;
    const int j  = blockIdx.x * 64 + tx;
    const int chunk = blockIdx.y * 4 + cz;            // 0..11
    const int b  = blockIdx.z;

    float lsum = 0.0f;
    if (j < OW) {
        const int i0 = chunk * 32;
        const int i1 = (i0 + 32 < OH) ? (i0 + 32) : OH;
        const float drv = drg[b];
        const float C1 = 1e-4f * drv * drv;           // (0.01*dr)^2
        const float C2 = 9e-4f * drv * drv;           // (0.03*dr)^2
        const float* Xp = Xg + (size_t)b * HH * WW_;
        const float* Yp = Yg + (size_t)b * HH * WW_;
        const u64*   Mp = Mg + (size_t)b * HH * WPR;
        const int w0i = j >> 6;
        const int w1i = (w0i + 1 < WPR) ? (w0i + 1) : (WPR - 1);
        const int sh  = j & 63;

        float r0[7], r1[7], r2[7], r3[7], r4[7];
        #pragma unroll
        for (int t = 0; t < 7; ++t) { r0[t]=0.f; r1[t]=0.f; r2[t]=0.f; r3[t]=0.f; r4[t]=0.f; }
        float vs0=0.f, vs1=0.f, vs2=0.f, vs3=0.f, vs4=0.f;

        const int rend = i1 + 6;
        for (int r = i0; r < rend; ++r) {
            const float* xr = Xp + (size_t)r * WW_ + j;
            const float* yr = Yp + (size_t)r * WW_ + j;
            u64 w0 = Mp[r * WPR + w0i];
            u64 w1 = Mp[r * WPR + w1i];
            // safe funnel: sh==0 -> second term 0 (each shift < 64)
            u64 win = (w0 >> sh) | ((w1 << 1) << (63 - sh));

            float h0=0.f,h1=0.f,h2=0.f,h3=0.f,h4=0.f;
            #pragma unroll
            for (int k = 0; k < 7; ++k) {
                float m = (float)((unsigned)(win >> k) & 1u);
                float xv = xr[k] * m;
                float yv = yr[k] * m;
                h0 += xv; h1 += yv;
                h2 = fmaf(xv, xv, h2);
                h3 = fmaf(yv, yv, h3);
                h4 = fmaf(xv, yv, h4);
            }
            vs0 += h0 - r0[0]; vs1 += h1 - r1[0]; vs2 += h2 - r2[0];
            vs3 += h3 - r3[0]; vs4 += h4 - r4[0];
            #pragma unroll
            for (int t = 0; t < 6; ++t) {
                r0[t]=r0[t+1]; r1[t]=r1[t+1]; r2[t]=r2[t+1]; r3[t]=r3[t+1]; r4[t]=r4[t+1];
            }
            r0[6]=h0; r1[6]=h1; r2[6]=h2; r3[6]=h3; r4[6]=h4;

            if (r >= i0 + 6) {
                const float inv49 = 1.0f / 49.0f;
                float ux  = vs0 * inv49, uy  = vs1 * inv49;
                float uxx = vs2 * inv49, uyy = vs3 * inv49, uxy = vs4 * inv49;
                float vx  = COVN * (uxx - ux*ux);
                float vy  = COVN * (uyy - uy*uy);
                float vxy = COVN * (uxy - ux*uy);
                float A1 = 2.0f*ux*uy + C1;
                float A2 = 2.0f*vxy + C2;
                float B1 = ux*ux + uy*uy + C1;
                float B2 = vx + vy + C2;
                lsum += (A1 * A2) / (B1 * B2);
            }
        }
    }

    __shared__ float sm[256];
    sm[threadIdx.x] = lsum;
    __syncthreads();
    #pragma unroll
    for (int off = 128; off > 0; off >>= 1) {
        if (threadIdx.x < off) sm[threadIdx.x] += sm[threadIdx.x + off];
        __syncthreads();
    }
    if (threadIdx.x == 0) {
        int flat = (blockIdx.z * 3 + blockIdx.y) * 6 + blockIdx.x;
        atomicAdd(&accum[flat & 1023], sm[0]);
    }
}

// ---------------- K8: finalize -> 1 - sum/N --------------------------------
__global__ void k_final(const float* __restrict__ accum, float* __restrict__ out) {
    __shared__ float sm[256];
    float v = 0.f;
    for (int i = threadIdx.x; i < 1024; i += 256) v += accum[i];
    sm[threadIdx.x] = v;
    __syncthreads();
    #pragma unroll
    for (int off = 128; off > 0; off >>= 1) {
        if (threadIdx.x < off) sm[threadIdx.x] += sm[threadIdx.x + off];
        __syncthreads();
    }
    if (threadIdx.x == 0) {
        out[0] = 1.0f - (float)((double)sm[0] / 18289152.0);  // N = 128*378*378
    }
}

extern "C" void kernel_launch(void* const* d_in, const int* in_sizes, int n_in,
                              void* d_out, int out_size, void* d_ws, size_t ws_size,
                              hipStream_t stream) {
    const float* X  = (const float*)d_in[0];
    const float* Y  = (const float*)d_in[1];
    const float* dr = (const float*)d_in[2];
    float* out = (float*)d_out;

    char* ws = (char*)d_ws;
    float* accum = (float*)ws;                                   // 4 KB
    u64* bufA = (u64*)(ws + 4096);                               // 2.36 MB
    u64* bufB = (u64*)(ws + 4096 + (size_t)WORDS_TOTAL * 8);     // 2.36 MB

    hipMemsetAsync(accum, 0, 1024 * sizeof(float), stream);

    k_binarize <<<PIX / 256,         256, 0, stream>>>(Y, bufA);
    k_erode3   <<<WORDS_TOTAL / 256, 256, 0, stream>>>(bufA, bufB);
    k_dilate_h15<<<WORDS_TOTAL / 256, 256, 0, stream>>>(bufB, bufA);
    k_dilate_v15<<<WORDS_TOTAL / 256, 256, 0, stream>>>(bufA, bufB);
    k_erode_h14<<<WORDS_TOTAL / 256, 256, 0, stream>>>(bufB, bufA);
    k_erode_v14<<<WORDS_TOTAL / 256, 256, 0, stream>>>(bufA, bufB);

    dim3 g(6, 3, 128);
    k_ssim<<<g, 256, 0, stream>>>(X, Y, dr, bufB, accum);
    k_final<<<1, 256, 0, stream>>>(accum, out);
}